// Round 8
// baseline (186.965 us; speedup 1.0000x reference)
//
#include <hip/hip_runtime.h>
#include <math.h>

#define CB 8
#define CNX 512
#define CNR 512
#define CD 256
#define CH 256

__device__ __forceinline__ float fast_rcp(float x) {
#if __has_builtin(__builtin_amdgcn_rcpf)
  return __builtin_amdgcn_rcpf(x);
#else
  return 1.0f / x;
#endif
}
__device__ __forceinline__ float fast_exp2(float x) {
#if __has_builtin(__builtin_amdgcn_exp2f)
  return __builtin_amdgcn_exp2f(x);
#else
  return exp2f(x);
#endif
}

// Fused projections.
// z=0: exT[b][h][x] = exp(2*(X@W_X^T+b_X))  (transposed layout, x contiguous)
// z=1: erN[b][r][h] = exp(2*(ref@W_ref^T+b_ref)) (natural layout, h contiguous)
// 64(m) x 64(h) tile, K-tile 16, grid (64,4,2), block 256, 4x4 microtile.
__global__ __launch_bounds__(256) void proj_fused(
    const float* __restrict__ A0, const float* __restrict__ A1,
    const float* __restrict__ W0, const float* __restrict__ W1,
    const float* __restrict__ bias0, const float* __restrict__ bias1,
    float* __restrict__ E0, float* __restrict__ E1) {
  __shared__ float As[16][68];  // [k][m] padded
  __shared__ float Ws[16][68];  // [k][h] padded
  const int K = CD;
  int z = blockIdx.z;
  const float* A = z ? A1 : A0;
  const float* W = z ? W1 : W0;
  const float* bias = z ? bias1 : bias0;
  int m0 = blockIdx.x * 64, n0 = blockIdx.y * 64;
  int tid = threadIdx.x;
  int tx = tid & 15, ty = tid >> 4;  // tx -> h, ty -> m
  int lrow = tid >> 2, lc4 = tid & 3;
  float acc[4][4] = {};
  const float* pA = A + (size_t)(m0 + lrow) * K + lc4 * 4;
  const float* pW = W + (size_t)(n0 + lrow) * K + lc4 * 4;
  float4 av = *(const float4*)(pA);
  float4 wv = *(const float4*)(pW);
  for (int kt = 0; kt < K; kt += 16) {
    if (kt) __syncthreads();
    As[lc4 * 4 + 0][lrow] = av.x;
    As[lc4 * 4 + 1][lrow] = av.y;
    As[lc4 * 4 + 2][lrow] = av.z;
    As[lc4 * 4 + 3][lrow] = av.w;
    Ws[lc4 * 4 + 0][lrow] = wv.x;
    Ws[lc4 * 4 + 1][lrow] = wv.y;
    Ws[lc4 * 4 + 2][lrow] = wv.z;
    Ws[lc4 * 4 + 3][lrow] = wv.w;
    __syncthreads();
    if (kt + 16 < K) {
      av = *(const float4*)(pA + kt + 16);
      wv = *(const float4*)(pW + kt + 16);
    }
#pragma unroll
    for (int k = 0; k < 16; k++) {
      float4 a4 = *(const float4*)&As[k][ty * 4];
      float4 w4 = *(const float4*)&Ws[k][tx * 4];
      float am[4] = {a4.x, a4.y, a4.z, a4.w};
      float wm[4] = {w4.x, w4.y, w4.z, w4.w};
#pragma unroll
      for (int i = 0; i < 4; i++)
#pragma unroll
        for (int j = 0; j < 4; j++)
          acc[i][j] = fmaf(am[i], wm[j], acc[i][j]);
    }
  }
  const float K2L = 2.8853900817779268f;  // 2*log2(e)
  float4 bv = *(const float4*)(bias + n0 + tx * 4);
  float bm[4] = {bv.x, bv.y, bv.z, bv.w};
  if (z == 0) {
    // transposed: exT[b][h][x]
    int b = m0 >> 9;
    int xbase = (m0 & 511) + ty * 4;
#pragma unroll
    for (int j = 0; j < 4; j++) {
      int h = n0 + tx * 4 + j;
      float4 o = {fast_exp2(K2L * (acc[0][j] + bm[j])),
                  fast_exp2(K2L * (acc[1][j] + bm[j])),
                  fast_exp2(K2L * (acc[2][j] + bm[j])),
                  fast_exp2(K2L * (acc[3][j] + bm[j]))};
      *(float4*)(E0 + ((size_t)b * CH + h) * CNX + xbase) = o;
    }
  } else {
    // natural: erN[m][h], m = b*512 + r
#pragma unroll
    for (int i = 0; i < 4; i++) {
      int m = m0 + ty * 4 + i;
      float4 o = {fast_exp2(K2L * (acc[i][0] + bm[0])),
                  fast_exp2(K2L * (acc[i][1] + bm[1])),
                  fast_exp2(K2L * (acc[i][2] + bm[2])),
                  fast_exp2(K2L * (acc[i][3] + bm[3]))};
      *(float4*)(E1 + (size_t)m * CH + n0 + tx * 4) = o;
    }
  }
}

// eT[b][r][x] = exp(-2 * sum_h v_w[h] / (exT[b][h][x]*erN[b][r][h] + 1))
// No LDS, no barriers: lanes carry x (per-lane coalesced ex loads);
// r and h indices are wave-uniform so er/v_w come via scalar loads (SMEM).
// grid (NX/64=8, NR/32=16, B=8) = 1024 blocks, 256 thr = 4 waves;
// wave wv handles r0 = by*32 + wv*8, 8 r's; 4-way h-merge.
__global__ __launch_bounds__(256) void scores_kernel(
    const float* __restrict__ exT, const float* __restrict__ erN,
    const float* __restrict__ v_w, float* __restrict__ eT) {
  int b = blockIdx.z;
  int tid = threadIdx.x;
  int lane = tid & 63;
  int wv = __builtin_amdgcn_readfirstlane(tid >> 6);
  int x = blockIdx.x * 64 + lane;
  int r0 = blockIdx.y * 32 + wv * 8;
  const float* pX = exT + (size_t)b * CH * CNX + x;
  const float* pR = erN + ((size_t)b * CNR + r0) * CH;
  float acc[8] = {};
  float exn[4];
#pragma unroll
  for (int k = 0; k < 4; k++) exn[k] = pX[(size_t)k * CNX];
#pragma unroll 2
  for (int hq = 0; hq < 64; hq++) {
    float exc[4];
#pragma unroll
    for (int k = 0; k < 4; k++) exc[k] = exn[k];
    if (hq < 63) {
#pragma unroll
      for (int k = 0; k < 4; k++) exn[k] = pX[(size_t)(hq * 4 + 4 + k) * CNX];
    }
    float4 vv = *(const float4*)(v_w + hq * 4);
#pragma unroll
    for (int r = 0; r < 8; r++) {
      float4 er = *(const float4*)(pR + (size_t)r * CH + hq * 4);
      float a  = fmaf(er.x, exc[0], 1.0f);
      float bb = fmaf(er.y, exc[1], 1.0f);
      float c  = fmaf(er.z, exc[2], 1.0f);
      float d  = fmaf(er.w, exc[3], 1.0f);
      float q12 = a * bb, q34 = c * d;
      float p12 = fmaf(vv.y, a, vv.x * bb);
      float p34 = fmaf(vv.w, c, vv.z * d);
      float num = fmaf(p34, q12, p12 * q34);
      acc[r] = fmaf(num, fast_rcp(q12 * q34), acc[r]);
    }
  }
  const float NL2E = -2.0f * 1.4426950408889634f;
  float* pO = eT + ((size_t)b * CNR + r0) * CNX + x;
#pragma unroll
  for (int r = 0; r < 8; r++)
    pO[(size_t)r * CNX] = fast_exp2(acc[r] * NL2E);
}

// out[b][r][d] = sum_x eT[b][r][x]*X[b][x][d] / sum_x eT[b][r][x]
// Same SGPR-broadcast structure: lanes = d, e[r][x] wave-uniform (s_load),
// X[x][d] per-lane coalesced. Denominator: lane-parallel pre-pass + butterfly.
// grid (CD/64=4, NR/32=16, B=8) = 512 blocks, 4 waves, 8 r/wave.
__global__ __launch_bounds__(256) void wsum_kernel(
    const float* __restrict__ eT, const float* __restrict__ X,
    float* __restrict__ out) {
  int b = blockIdx.z;
  int tid = threadIdx.x;
  int lane = tid & 63;
  int wv = __builtin_amdgcn_readfirstlane(tid >> 6);
  int d = blockIdx.x * 64 + lane;
  int r0 = blockIdx.y * 32 + wv * 8;
  const float* pE = eT + ((size_t)b * CNR + r0) * CNX;
  const float* pX = X + (size_t)b * CNX * CD + d;
  // denominators: each lane sums 8 elements of the row, butterfly-reduce
  float inv[8];
#pragma unroll
  for (int r = 0; r < 8; r++) {
    const float4* row = (const float4*)(pE + (size_t)r * CNX);
    float4 ea = row[lane];
    float4 eb = row[lane + 64];
    float s = ((ea.x + ea.y) + (ea.z + ea.w)) + ((eb.x + eb.y) + (eb.z + eb.w));
#pragma unroll
    for (int off = 1; off < 64; off <<= 1) s += __shfl_xor(s, off, 64);
    inv[r] = fast_rcp(s);
  }
  float acc[8] = {};
  float xn[4];
#pragma unroll
  for (int k = 0; k < 4; k++) xn[k] = pX[(size_t)k * CD];
#pragma unroll 2
  for (int xq = 0; xq < 128; xq++) {
    float xc[4];
#pragma unroll
    for (int k = 0; k < 4; k++) xc[k] = xn[k];
    if (xq < 127) {
#pragma unroll
      for (int k = 0; k < 4; k++) xn[k] = pX[(size_t)(xq * 4 + 4 + k) * CD];
    }
#pragma unroll
    for (int r = 0; r < 8; r++) {
      float4 e4 = *(const float4*)(pE + (size_t)r * CNX + xq * 4);
      acc[r] = fmaf(e4.x, xc[0], acc[r]);
      acc[r] = fmaf(e4.y, xc[1], acc[r]);
      acc[r] = fmaf(e4.z, xc[2], acc[r]);
      acc[r] = fmaf(e4.w, xc[3], acc[r]);
    }
  }
  float* pO = out + ((size_t)b * CNR + r0) * CD + d;
#pragma unroll
  for (int r = 0; r < 8; r++)
    pO[(size_t)r * CD] = acc[r] * inv[r];
}

extern "C" void kernel_launch(void* const* d_in, const int* in_sizes, int n_in,
                              void* d_out, int out_size, void* d_ws, size_t ws_size,
                              hipStream_t stream) {
  const float* X     = (const float*)d_in[0];
  const float* ref   = (const float*)d_in[1];
  const float* W_X   = (const float*)d_in[2];
  const float* b_X   = (const float*)d_in[3];
  const float* W_ref = (const float*)d_in[4];
  const float* b_ref = (const float*)d_in[5];
  const float* v_w   = (const float*)d_in[6];
  float* out = (float*)d_out;
  float* ws  = (float*)d_ws;

  float* exT = ws;                       // [B][H][NX] = 1,048,576 floats
  float* erN = ws + 1048576;             // [B][NR][H] = 1,048,576 floats
  float* eT  = ws + 2097152;             // [B][NR][NX] = 2,097,152 floats

  proj_fused<<<dim3(64, 4, 2), 256, 0, stream>>>(X, ref, W_X, W_ref, b_X, b_ref, exT, erN);
  scores_kernel<<<dim3(8, 16, 8), 256, 0, stream>>>(exT, erN, v_w, eT);
  wsum_kernel<<<dim3(4, 16, 8), 256, 0, stream>>>(eT, X, out);
}